// Round 10
// baseline (17332.466 us; speedup 1.0000x reference)
//
#include <hip/hip_runtime.h>

#define T_STEPS 8192
#define HID 256
#define NBLK 128      // dispatched; 16 co-located on one elected XCD participate
#define THREADS 256   // 4 waves (R5-proven roles)
#define SPIN_T0  4096 // t==0 poll budget (startup skew)
#define SPIN_RUN 64   // t>0 poll rounds before sticky demotion to agent path
#define SLOW_N   8    // a step needing >SLOW_N rounds counts as "slow"
#define SLOW_CAP 512  // cumulative slow steps -> demote (R3 lesson)

#define MAGIC_READY 0x13579BDFu
#define EMPTY_XCD   0xFFFFFFFFu
#define DONE_MAGIC  0x600DD00Eu

typedef float v4f __attribute__((ext_vector_type(4)));

// 2/(1+e^-2x)-1 is inf-safe at both ends
__device__ __forceinline__ float tanh_fast(float x) { return 2.0f / (1.0f + __expf(-2.0f * x)) - 1.0f; }

// sc0 store: commit toward the XCD-local L2 (R5-passed producer flavor).
__device__ __forceinline__ void st_u64_sc0(unsigned long long* p, unsigned long long v) {
    asm volatile("global_store_dwordx2 %0, %1, off sc0" :: "v"(p), "v"(v) : "memory");
}
// Invalidate the CU's (write-through) vector L1 so sc0 loads re-probe the L2.
__device__ __forceinline__ void inv_l1() { asm volatile("buffer_inv sc0" ::: "memory"); }
__device__ __forceinline__ void ld4_issue_sc0(const unsigned long long* p,
                                              unsigned long long& a, unsigned long long& b,
                                              unsigned long long& c, unsigned long long& d) {
    asm volatile(
        "global_load_dwordx2 %0, %4, off sc0\n\t"
        "global_load_dwordx2 %1, %4, off offset:8 sc0\n\t"
        "global_load_dwordx2 %2, %4, off offset:16 sc0\n\t"
        "global_load_dwordx2 %3, %4, off offset:24 sc0"
        : "=&v"(a), "=&v"(b), "=&v"(c), "=&v"(d)
        : "v"(p) : "memory");
}
// vmcnt(0) + dataflow-bind (rule-18: "memory" alone doesn't order reg reads of asm outputs)
__device__ __forceinline__ void vm_wait0_bind(unsigned long long& a, unsigned long long& b,
                                              unsigned long long& c, unsigned long long& d) {
    asm volatile("s_waitcnt vmcnt(0)" ::: "memory");
    __builtin_amdgcn_sched_barrier(0);
    asm volatile("" : "+v"(a), "+v"(b), "+v"(c), "+v"(d));
}
__device__ __forceinline__ void ld_e4_issue(const float* p, v4f& e) {
    asm volatile("global_load_dwordx4 %0, %1, off" : "=v"(e) : "v"(p) : "memory");
}
__device__ __forceinline__ bool tags_ok(unsigned long long a, unsigned long long b,
                                        unsigned long long c, unsigned long long d, unsigned tt) {
    return ((unsigned)(a >> 32) == tt) & ((unsigned)(b >> 32) == tt) &
           ((unsigned)(c >> 32) == tt) & ((unsigned)(d >> 32) == tt);
}
// Raw barrier WITHOUT the __syncthreads vmcnt(0) drain: store acks keep flying.
// LDS producers (h-writer wave0, e-writer wave1) drain lgkm only.
__device__ __forceinline__ void bar_producer() {
    __builtin_amdgcn_sched_barrier(0);
    asm volatile("s_waitcnt lgkmcnt(0)" ::: "memory");
    __builtin_amdgcn_s_barrier();
    __builtin_amdgcn_sched_barrier(0);
}
__device__ __forceinline__ void bar_plain() {
    __builtin_amdgcn_sched_barrier(0);
    __builtin_amdgcn_s_barrier();
    __builtin_amdgcn_sched_barrier(0);
}

__global__ __launch_bounds__(THREADS, 1)
void lstm_scan(const int* __restrict__ tokens,
               const float* __restrict__ emb,    // [V,256] fp32
               const float* __restrict__ Wih,    // [1024,256] fp32
               const float* __restrict__ Whh,    // [1024,256] fp32
               const float* __restrict__ bih,    // [1024]
               const float* __restrict__ bhh,    // [1024]
               float* __restrict__ out,          // [T*256 + 256 + 256] fp32
               unsigned long long* __restrict__ hbL,   // ws+0:    [2][256] local-L2 channel
               unsigned long long* __restrict__ hbA,   // ws+4096: [2][256] agent fallback
               unsigned* __restrict__ ctl)             // ws+8192: ready, elected, cnt[8], done
{
    // ---- XCD election: find 16 blocks co-located on one XCD (pigeonhole over 128) ----
    __shared__ int s_role;
    if (threadIdx.x == 0) {
        unsigned xcc;
        asm volatile("s_getreg_b32 %0, hwreg(HW_REG_XCC_ID, 0, 4)" : "=s"(xcc));
        unsigned* ready   = ctl + 0;
        unsigned* elected = ctl + 1;
        unsigned* cnt     = ctl + 2;   // [8]
        if (blockIdx.x == 0) {
            for (int i = 0; i < 8; ++i)
                __hip_atomic_store(cnt + i, 0u, __ATOMIC_RELAXED, __HIP_MEMORY_SCOPE_AGENT);
            __hip_atomic_store(elected, EMPTY_XCD, __ATOMIC_RELAXED, __HIP_MEMORY_SCOPE_AGENT);
            __hip_atomic_store(ctl + 10, 0u, __ATOMIC_RELAXED, __HIP_MEMORY_SCOPE_AGENT); // done
            __hip_atomic_store(ready, MAGIC_READY, __ATOMIC_RELEASE, __HIP_MEMORY_SCOPE_AGENT);
        }
        while (__hip_atomic_load(ready, __ATOMIC_ACQUIRE, __HIP_MEMORY_SCOPE_AGENT) != MAGIC_READY)
            asm volatile("s_sleep 1");
        unsigned r = __hip_atomic_fetch_add(cnt + xcc, 1u, __ATOMIC_RELAXED, __HIP_MEMORY_SCOPE_AGENT);
        if (r == 15u) {
            unsigned expv = EMPTY_XCD;
            __hip_atomic_compare_exchange_strong(elected, &expv, xcc,
                __ATOMIC_RELAXED, __ATOMIC_RELAXED, __HIP_MEMORY_SCOPE_AGENT);
        }
        unsigned e;
        while ((e = __hip_atomic_load(elected, __ATOMIC_ACQUIRE, __HIP_MEMORY_SCOPE_AGENT)) == EMPTY_XCD)
            asm volatile("s_sleep 1");
        s_role = (xcc == e && r < 16u) ? (int)r : -1;
    }
    __syncthreads();
    const int w = s_role;          // role 0..15, or -1 = anti-DVFS spinner

    if (w < 0) {
        // Bystanders keep the clock governor awake with pure-register VALU work.
        float x0 = 1.0f, x1 = 2.0f, x2 = 3.0f, x3 = 4.0f;
        const float a = 1.0000001f, b = 1e-7f;
        const unsigned* done = ctl + 10;
        for (;;) {
            #pragma unroll 64
            for (int i = 0; i < 512; ++i) {
                x0 = fmaf(x0, a, b); x1 = fmaf(x1, a, b);
                x2 = fmaf(x2, a, b); x3 = fmaf(x3, a, b);
            }
            if (__hip_atomic_load(done, __ATOMIC_RELAXED, __HIP_MEMORY_SCOPE_AGENT) == DONE_MAGIC)
                break;
        }
        asm volatile("" :: "v"(x0 + x1 + x2 + x3));
        return;
    }

    // ---- scan body: R5 skeleton + {raw barrier, depth-2 emb pipe, clean wave0 queue} ----
    const int tid  = threadIdx.x;
    const int lane = tid & 63;
    const int wave = tid >> 6;         // 0..3
    const int rl   = lane >> 2;        // row-within-wave 0..15
    const int kq   = lane & 3;         // k-quarter 0..3
    const int r_wg = wave * 16 + rl;   // local gate-row 0..63
    const int unit = w * 16 + (r_wg >> 2);     // global hidden unit 0..255
    const int gate = r_wg & 3;                 // 0=i 1=f 2=cell 3=o
    const int grow = gate * 256 + unit;        // global gate row 0..1023
    const int kbase = kq * 64;

    float whh[64], wih[64];
    {
        const float* p = Whh + (size_t)grow * 256 + kbase;
        #pragma unroll
        for (int j = 0; j < 64; j += 4) {
            float4 q = *(const float4*)(p + j);
            whh[j] = q.x; whh[j+1] = q.y; whh[j+2] = q.z; whh[j+3] = q.w;
        }
        p = Wih + (size_t)grow * 256 + kbase;
        #pragma unroll
        for (int j = 0; j < 64; j += 4) {
            float4 q = *(const float4*)(p + j);
            wih[j] = q.x; wih[j+1] = q.y; wih[j+2] = q.z; wih[j+3] = q.w;
        }
    }
    const float bias = bih[grow] + bhh[grow];
    const bool owner = ((lane & 15) == 0);             // 4 owners per wave
    const float act_scale = (gate == 2) ? 2.0f : 1.0f;
    const float act_off   = (gate == 2) ? 1.0f : 0.0f;

    __shared__ v4f lds_h[2][4][17];               // h parity double-buffer
    __shared__ v4f lds_e[2][4][17];               // emb parity double-buffer
    __shared__ __align__(16) int s_tok[T_STEPS];  // 32KB: token lookups off the vm queue

    for (int i = tid; i < T_STEPS / 4; i += THREADS)
        *(int4*)&s_tok[i * 4] = *(const int4*)&tokens[i * 4];

    // prologue: owners publish h=0/tag0 into parity-0 of BOTH buffers; wave1 stages
    // emb(0) and preloads emb(1) into the pipeline register (plain synchronous loads).
    if (owner) {
        st_u64_sc0(hbL + unit, 0ull);
        __hip_atomic_store(hbA + unit, 0ull, __ATOMIC_RELAXED, __HIP_MEMORY_SCOPE_AGENT);
    }
    v4f e_pipe;   // wave1: holds emb(t+1) at top of iter t
    if (wave == 1) {
        int tk0 = tokens[0];
        v4f e0 = *(const v4f*)(emb + (size_t)tk0 * 256 + lane * 4);
        lds_e[0][lane >> 4][lane & 15] = e0;
        int tk1 = tokens[1];
        e_pipe = *(const v4f*)(emb + (size_t)tk1 * 256 + lane * 4);
    }
    float c = 0.0f;
    bool useL2 = true;   // sticky demotion (wave 0 lanes)
    int  slow  = 0;
    unsigned long long pk_prev = 0ull;   // wave0 owners: deferred hbA (tag t at top of iter t)
    __syncthreads();     // full barrier once: s_tok/lds_e visible, init publishes drained

    for (int t = 0; t < T_STEPS; ++t) {
        const unsigned tt = (unsigned)t;
        // ---- pre-barrier phase ----
        unsigned long long q0 = 0, q1 = 0, q2 = 0, q3 = 0;
        unsigned long long* hbp = hbL + (size_t)(t & 1) * 256 + lane * 4;
        if (wave == 0 && useL2) {          // issue poll early; flight hides under wih FMAs
            inv_l1();
            ld4_issue_sc0(hbp, q0, q1, q2, q3);
        }
        if (wave == 1) {
            // e_pipe = emb(t+1): retired by LAST iter's tail wait (bound there).
            lds_e[(t + 1) & 1][lane >> 4][lane & 15] = e_pipe;
            int nt = t + 2; if (nt > T_STEPS - 1) nt = T_STEPS - 1;
            ld_e4_issue(emb + (size_t)s_tok[nt] * 256 + lane * 4, e_pipe);  // full step of flight
        }
        // wih . emb(t) — 4 independent chains (all waves)
        float aA = 0.0f, aB = 0.0f, aC = 0.0f, aD = 0.0f;
        {
            const v4f* eb = &lds_e[t & 1][kq][0];
            #pragma unroll
            for (int i = 0; i < 16; i += 4) {
                v4f v0 = eb[i], v1 = eb[i+1], v2 = eb[i+2], v3 = eb[i+3];
                aA = fmaf(wih[4*i+ 0], v0[0], aA); aA = fmaf(wih[4*i+ 1], v0[1], aA);
                aA = fmaf(wih[4*i+ 2], v0[2], aA); aA = fmaf(wih[4*i+ 3], v0[3], aA);
                aB = fmaf(wih[4*i+ 4], v1[0], aB); aB = fmaf(wih[4*i+ 5], v1[1], aB);
                aB = fmaf(wih[4*i+ 6], v1[2], aB); aB = fmaf(wih[4*i+ 7], v1[3], aB);
                aC = fmaf(wih[4*i+ 8], v2[0], aC); aC = fmaf(wih[4*i+ 9], v2[1], aC);
                aC = fmaf(wih[4*i+10], v2[2], aC); aC = fmaf(wih[4*i+11], v2[3], aC);
                aD = fmaf(wih[4*i+12], v3[0], aD); aD = fmaf(wih[4*i+13], v3[1], aD);
                aD = fmaf(wih[4*i+14], v3[2], aD); aD = fmaf(wih[4*i+15], v3[3], aD);
            }
        }
        if (wave == 0) {
            bool got = false;
            if (useL2) {
                vm_wait0_bind(q0, q1, q2, q3);     // FIRST CHECK: queue = 4 loads only (pure)
                got = tags_ok(q0, q1, q2, q3, tt);
            }
            // deferred hbA publish (tag t) AFTER the pure first check; guarantees
            // own-block fallback liveness and bounded cross-block fallback lag.
            if (owner)
                __hip_atomic_store(hbA + (size_t)(t & 1) * 256 + unit, pk_prev,
                                   __ATOMIC_RELAXED, __HIP_MEMORY_SCOPE_AGENT);
            if (useL2 && !got) {
                const int smax = (t == 0) ? SPIN_T0 : SPIN_RUN;
                int n = 0;
                for (;;) {
                    inv_l1();
                    ld4_issue_sc0(hbp, q0, q1, q2, q3);
                    vm_wait0_bind(q0, q1, q2, q3);   // rounds 1-2 may absorb hbA ack, then pure
                    if (tags_ok(q0, q1, q2, q3, tt)) { got = true; break; }
                    if (++n > smax) { useL2 = false; break; }
                }
                if (got && t > 0 && n > SLOW_N) { if (++slow > SLOW_CAP) useL2 = false; }
            }
            if (!got) {   // proven agent/IF channel (baseline formulation), unbounded
                const unsigned long long* ha = hbA + (size_t)(t & 1) * 256 + lane * 4;
                for (;;) {
                    q0 = __hip_atomic_load(ha + 0, __ATOMIC_RELAXED, __HIP_MEMORY_SCOPE_AGENT);
                    q1 = __hip_atomic_load(ha + 1, __ATOMIC_RELAXED, __HIP_MEMORY_SCOPE_AGENT);
                    q2 = __hip_atomic_load(ha + 2, __ATOMIC_RELAXED, __HIP_MEMORY_SCOPE_AGENT);
                    q3 = __hip_atomic_load(ha + 3, __ATOMIC_RELAXED, __HIP_MEMORY_SCOPE_AGENT);
                    if (tags_ok(q0, q1, q2, q3, tt)) break;
                }
            }
            union { unsigned i; float f; } ua, ub, uc, ud;
            ua.i = (unsigned)q0; ub.i = (unsigned)q1; uc.i = (unsigned)q2; ud.i = (unsigned)q3;
            v4f hv; hv[0] = ua.f; hv[1] = ub.f; hv[2] = uc.f; hv[3] = ud.f;
            lds_h[t & 1][lane >> 4][lane & 15] = hv;
        }
        // RAW barrier: no vmcnt drain -> waves 1-3's store acks fly across it.
        if (wave <= 1) bar_producer(); else bar_plain();
        // ---- post-barrier phase ----
        {
            const v4f* hq = &lds_h[t & 1][kq][0];
            #pragma unroll
            for (int i = 0; i < 16; i += 4) {
                v4f v0 = hq[i], v1 = hq[i+1], v2 = hq[i+2], v3 = hq[i+3];
                aA = fmaf(whh[4*i+ 0], v0[0], aA); aA = fmaf(whh[4*i+ 1], v0[1], aA);
                aA = fmaf(whh[4*i+ 2], v0[2], aA); aA = fmaf(whh[4*i+ 3], v0[3], aA);
                aB = fmaf(whh[4*i+ 4], v1[0], aB); aB = fmaf(whh[4*i+ 5], v1[1], aB);
                aB = fmaf(whh[4*i+ 6], v1[2], aB); aB = fmaf(whh[4*i+ 7], v1[3], aB);
                aC = fmaf(whh[4*i+ 8], v2[0], aC); aC = fmaf(whh[4*i+ 9], v2[1], aC);
                aC = fmaf(whh[4*i+10], v2[2], aC); aC = fmaf(whh[4*i+11], v2[3], aC);
                aD = fmaf(whh[4*i+12], v3[0], aD); aD = fmaf(whh[4*i+13], v3[1], aD);
                aD = fmaf(whh[4*i+14], v3[2], aD); aD = fmaf(whh[4*i+15], v3[3], aD);
            }
        }
        float acc = (aA + aB) + (aC + aD);
        acc += __shfl_xor(acc, 1, 64);
        acc += __shfl_xor(acc, 2, 64);
        acc += bias;
        float ex = __expf(-act_scale * acc);
        float av = act_scale / (1.0f + ex) - act_off;   // sigm gates 0/1/3, tanh gate 2
        const int base = lane & 48;
        float fv = __shfl(av, base + 4,  64);
        float gv = __shfl(av, base + 8,  64);
        float ov = __shfl(av, base + 12, 64);
        float h = 0.0f;
        unsigned long long pk = 0ull;
        size_t so = 0;
        if (owner) {
            c = fmaf(fv, c, av * gv);
            h = ov * tanh_fast(c);
            union { unsigned i; float f; } u; u.f = h;
            pk = (((unsigned long long)(unsigned)(t + 1)) << 32) | (unsigned long long)u.i;
            so = (size_t)((t + 1) & 1) * 256 + unit;
            st_u64_sc0(hbL + so, pk);          // fast channel, issued FIRST
        }
        // Wave-wide prompt commit: retires only this wave's hbL (older ops retired a
        // full step ago) -> ~300cy, and the value is IN the local L2 now (visibility
        // forcing). Wave1 additionally binds its emb pipeline register here.
        if (wave == 1) {
            asm volatile("s_waitcnt vmcnt(0)" : "+v"(e_pipe) :: "memory");
        } else {
            asm volatile("s_waitcnt vmcnt(0)" ::: "memory");
        }
        __builtin_amdgcn_sched_barrier(0);
        if (owner) {
            if (wave != 0)                      // waves 1-3: direct hbA publish (ack flies)
                __hip_atomic_store(hbA + so, pk, __ATOMIC_RELAXED, __HIP_MEMORY_SCOPE_AGENT);
            else
                pk_prev = pk;                   // wave0: deferred to next iter top
            out[(size_t)t * HID + unit] = h;    // after commit: retires lazily
            if (t == T_STEPS - 1) {
                out[(size_t)T_STEPS * HID + unit]       = h;  // h_last
                out[(size_t)T_STEPS * HID + HID + unit] = c;  // c_last
            }
        }
    }

    if (w == 0 && tid == 0) {
        // release the anti-DVFS spinners, then re-arm the election protocol
        __hip_atomic_store(ctl + 10, DONE_MAGIC, __ATOMIC_RELEASE, __HIP_MEMORY_SCOPE_AGENT);
        __hip_atomic_store(ctl + 0, 0u, __ATOMIC_RELAXED, __HIP_MEMORY_SCOPE_AGENT);
    }
}

extern "C" void kernel_launch(void* const* d_in, const int* in_sizes, int n_in,
                              void* d_out, int out_size, void* d_ws, size_t ws_size,
                              hipStream_t stream) {
    const int*   tokens = (const int*)d_in[0];
    const float* emb    = (const float*)d_in[1];
    const float* Wih    = (const float*)d_in[2];
    const float* Whh    = (const float*)d_in[3];
    const float* bih    = (const float*)d_in[4];
    const float* bhh    = (const float*)d_in[5];
    float* out = (float*)d_out;
    unsigned long long* hbL = (unsigned long long*)d_ws;                    // [2][256] u64
    unsigned long long* hbA = (unsigned long long*)((char*)d_ws + 4096);    // [2][256] u64
    unsigned* ctl = (unsigned*)((char*)d_ws + 8192);                        // election/done

    lstm_scan<<<NBLK, THREADS, 0, stream>>>(tokens, emb, Wih, Whh, bih, bhh, out, hbL, hbA, ctl);
}